// Round 13
// baseline (198.319 us; speedup 1.0000x reference)
//
#include <hip/hip_runtime.h>

#define QSCALE 44.0f

// ---------- helpers ----------
__device__ __forceinline__ unsigned short f2bf(float f) {
    unsigned u = __float_as_uint(f);
    unsigned r = (u + 0x7fffu + ((u >> 16) & 1u)) >> 16;   // RNE
    return (unsigned short)r;
}
__device__ __forceinline__ float bfu(unsigned short s) {
    return __uint_as_float(((unsigned)s) << 16);
}

// int8 dot over one dword pair: acc += w[i] * relu(a_i + b_i)
__device__ __forceinline__ float dot4_i8(unsigned ax, unsigned bx, const float* w) {
    float acc = 0.f;
#pragma unroll
    for (int i = 0; i < 4; ++i) {
        int va = (int)(char)(ax >> (8 * i));
        int vb = (int)(char)(bx >> (8 * i));
        acc += w[i] * (float)max(va + vb, 0);
    }
    return acc;
}

// full 16-element lane dot + 8-lane reduce -> full 128-dim logit (pre-bias)
__device__ __forceinline__ float edge_dot(const uint4& a, const uint4& b, const float* w2r) {
    float acc;
    acc  = dot4_i8(a.x, b.x, w2r + 0);
    acc += dot4_i8(a.y, b.y, w2r + 4);
    acc += dot4_i8(a.z, b.z, w2r + 8);
    acc += dot4_i8(a.w, b.w, w2r + 12);
    acc += __shfl_xor(acc, 1);
    acc += __shfl_xor(acc, 2);
    acc += __shfl_xor(acc, 4);
    return acc;
}

// packed fixed-point encode: lo = ev*2^16 (u32), hi = y*ev*2^14 (i32)
__device__ __forceinline__ unsigned long long pack_contrib(float ev, float ys) {
    float flo = fminf(ev * 65536.f, 1.0e9f);
    float fhi = fmaxf(fminf(ys * ev * 16384.f, 1.0e9f), -1.0e9f);
    unsigned int qlo = (unsigned int)__float2int_rn(flo);
    int          qhi = __float2int_rn(fhi);
    return ((unsigned long long)(unsigned int)qhi << 32) | (unsigned long long)qlo;
}

__device__ __forceinline__ int q8(float v) {
    return __float2int_rn(fminf(fmaxf(v * QSCALE, -127.f), 127.f)) & 0xff;
}

// ---------- grid-wide ticket barrier (R3/R5/R11-proven; runtime block count) ----------
__device__ __forceinline__ void grid_sync(unsigned long long* bar, int nblk) {
    __syncthreads();
    if (threadIdx.x == 0) {
        __threadfence();   // release
        unsigned long long t = atomicAdd(bar, 1ull) + 1ull;
        unsigned long long nb = (unsigned long long)nblk;
        unsigned long long target = ((t + nb - 1ull) / nb) * nb;
        while (__hip_atomic_load(bar, __ATOMIC_RELAXED, __HIP_MEMORY_SCOPE_AGENT) < target)
            __builtin_amdgcn_s_sleep(2);
        __threadfence();   // acquire
    }
    __syncthreads();
}

// ---------- edge phase body — R0 single-edge form (proven 85.2us @ VGPR 24) + bf16 ev ----------
// R1 proved depth-4 unroll changes nothing (L2-miss-rate-bound, not latency-bound);
// single-edge keeps live VGPR minimal so the fused coop kernel stays <=64 VGPR naturally.
__device__ __forceinline__ void edge_phase(
    const unsigned char* __restrict__ P, const int* __restrict__ ei,
    const float* __restrict__ y, const float* __restrict__ w2,
    const float* __restrict__ b2, unsigned short* __restrict__ evh,
    unsigned long long* __restrict__ agg, int E, int gtid, int nthreads)
{
    const int lane = gtid & 7;
    float w2r[16];
#pragma unroll
    for (int c = 0; c < 16; ++c) w2r[c] = w2[lane * 16 + c] * (1.0f / QSCALE);
    const float b2s = b2[0];

    const int slot = gtid >> 3;
    const int nslots = nthreads >> 3;
    const int lo16 = lane * 16;

    for (int e = slot; e < E; e += nslots) {
        const int s = ei[e];
        const int d = ei[E + e];
        const uint4 a = *(const uint4*)(P + (size_t)s * 256 + lo16);
        const uint4 b = *(const uint4*)(P + (size_t)d * 256 + 128 + lo16);

        const float acc = edge_dot(a, b, w2r);

        if (lane == 0) {
            const float ev = __expf(acc + b2s);
            evh[e] = f2bf(ev);
            atomicAdd(&agg[d], pack_contrib(ev, y[s]));
        }
    }
}

// ---------- decode phase body (R10-proven) ----------
__device__ __forceinline__ void decode_phase(
    const int* __restrict__ ei, const unsigned long long* __restrict__ agg,
    const unsigned short* __restrict__ evh, float* __restrict__ alpha,
    float* __restrict__ yhat, int N, int E, int gtid, int ntot)
{
    for (int i = gtid; i < N; i += ntot) {
        unsigned long long v = agg[i];
        unsigned int lo = (unsigned int)(v & 0xffffffffull);
        int          hi = (int)(v >> 32);
        yhat[i] = (lo != 0u) ? 4.0f * (float)hi / (float)lo : 0.f;   // (hi/2^14)/(lo/2^16)
    }

    for (int base = gtid * 4; base < E; base += ntot * 4) {
        if (base + 3 < E) {
            const int4 d4 = *(const int4*)&ei[E + base];
            const ushort4 eh = *(const ushort4*)&evh[base];
            const unsigned int l0 = (unsigned int)(agg[d4.x] & 0xffffffffull);
            const unsigned int l1 = (unsigned int)(agg[d4.y] & 0xffffffffull);
            const unsigned int l2 = (unsigned int)(agg[d4.z] & 0xffffffffull);
            const unsigned int l3 = (unsigned int)(agg[d4.w] & 0xffffffffull);
            float4 av;
            av.x = l0 ? bfu(eh.x) * (65536.0f / (float)l0) : 0.f;
            av.y = l1 ? bfu(eh.y) * (65536.0f / (float)l1) : 0.f;
            av.z = l2 ? bfu(eh.z) * (65536.0f / (float)l2) : 0.f;
            av.w = l3 ? bfu(eh.w) * (65536.0f / (float)l3) : 0.f;
            *(float4*)&alpha[base] = av;
        } else {
            for (int e = base; e < E; ++e) {
                const unsigned int lo = (unsigned int)(agg[ei[E + e]] & 0xffffffffull);
                alpha[e] = lo ? bfu(evh[e]) * (65536.0f / (float)lo) : 0.f;
            }
        }
    }
}

// ---------- kernel 1: node projection v3b (R9-proven) — FROZEN ----------
__global__ __launch_bounds__(256) void proj_kernel(
    const float* __restrict__ x, const float* __restrict__ w1, const float* __restrict__ b1,
    unsigned char* __restrict__ P, unsigned long long* __restrict__ agg, int N)
{
    __shared__ float xs[64 * 65];                 // 16.6 KB
    const int t = threadIdx.x;
    const int nloc = t & 63;
    const int n = blockIdx.x * 64 + nloc;
    const int j0 = __builtin_amdgcn_readfirstlane((t >> 6) * 32);   // wave-uniform -> SGPR

    if (t < 64) {
        int nn = blockIdx.x * 64 + t;
        if (nn < N) agg[nn] = 0ull;
    }

    for (int i4 = t; i4 < 64 * 16; i4 += 256) {
        const int row = i4 >> 4, c4 = (i4 & 15) * 4;
        const int nn = blockIdx.x * 64 + row;
        float4 v = make_float4(0.f, 0.f, 0.f, 0.f);
        if (nn < N) v = *(const float4*)&x[(size_t)nn * 64 + c4];
        float* d = &xs[row * 65 + c4];
        d[0] = v.x; d[1] = v.y; d[2] = v.z; d[3] = v.w;
    }
    __syncthreads();

    float accA[32], accB[32];
#pragma unroll
    for (int c = 0; c < 32; ++c) { accA[c] = b1[j0 + c]; accB[c] = 0.f; }

    const float* __restrict__ xrow = &xs[nloc * 65];
    for (int k = 0; k < 64; ++k) {
        const float xv = xrow[k];
        const float* __restrict__ wa = w1 + k * 128 + j0;          // uniform -> s_load
        const float* __restrict__ wb = w1 + (64 + k) * 128 + j0;   // uniform -> s_load
#pragma unroll
        for (int c = 0; c < 32; ++c) {
            accA[c] = fmaf(xv, wa[c], accA[c]);
            accB[c] = fmaf(xv, wb[c], accB[c]);
        }
    }

    if (n < N) {
        unsigned dwA[8], dwB[8];
#pragma unroll
        for (int d = 0; d < 8; ++d) {
            dwA[d] = (unsigned)q8(accA[d * 4 + 0])
                   | ((unsigned)q8(accA[d * 4 + 1]) << 8)
                   | ((unsigned)q8(accA[d * 4 + 2]) << 16)
                   | ((unsigned)q8(accA[d * 4 + 3]) << 24);
            dwB[d] = (unsigned)q8(accB[d * 4 + 0])
                   | ((unsigned)q8(accB[d * 4 + 1]) << 8)
                   | ((unsigned)q8(accB[d * 4 + 2]) << 16)
                   | ((unsigned)q8(accB[d * 4 + 3]) << 24);
        }
        unsigned char* pA = P + (size_t)n * 256 + j0;
        unsigned char* pB = P + (size_t)n * 256 + 128 + j0;
        *(uint4*)(pA)      = make_uint4(dwA[0], dwA[1], dwA[2], dwA[3]);
        *(uint4*)(pA + 16) = make_uint4(dwA[4], dwA[5], dwA[6], dwA[7]);
        *(uint4*)(pB)      = make_uint4(dwB[0], dwB[1], dwB[2], dwB[3]);
        *(uint4*)(pB + 16) = make_uint4(dwB[4], dwB[5], dwB[6], dwB[7]);
    }
}

// ---------- cooperative fused kernel: edge -> [grid sync] -> decode ----------
// Single-edge body keeps natural VGPR ~32-40 (<=64) -> 8 blocks/CU without coercion.
__global__ __launch_bounds__(256) void edge_decode_coop_kernel(
    const unsigned char* __restrict__ P, const int* __restrict__ ei,
    const float* __restrict__ y, const float* __restrict__ w2,
    const float* __restrict__ b2, unsigned short* __restrict__ evh,
    unsigned long long* __restrict__ agg, unsigned long long* __restrict__ bar,
    float* __restrict__ alpha, float* __restrict__ yhat, int N, int E, int nblk)
{
    const int gtid = blockIdx.x * 256 + threadIdx.x;
    const int nthreads = nblk * 256;
    edge_phase(P, ei, y, w2, b2, evh, agg, E, gtid, nthreads);
    grid_sync(bar, nblk);
    decode_phase(ei, agg, evh, alpha, yhat, N, E, gtid, nthreads);
}

// ---------- fallback kernels (same proven bodies) ----------
__global__ __launch_bounds__(256) void edge_logit_kernel(
    const unsigned char* __restrict__ P, const int* __restrict__ ei,
    const float* __restrict__ y,
    const float* __restrict__ w2, const float* __restrict__ b2,
    unsigned short* __restrict__ evh, unsigned long long* __restrict__ agg, int E)
{
    const int gtid = blockIdx.x * 256 + threadIdx.x;
    edge_phase(P, ei, y, w2, b2, evh, agg, E, gtid, gridDim.x * 256);
}

__global__ __launch_bounds__(256) void decode_alpha_kernel(
    const int* __restrict__ ei, const unsigned long long* __restrict__ agg,
    const unsigned short* __restrict__ evh, float* __restrict__ alpha,
    float* __restrict__ yhat, int N, int E)
{
    const int gtid = blockIdx.x * 256 + threadIdx.x;
    decode_phase(ei, agg, evh, alpha, yhat, N, E, gtid, gridDim.x * 256);
}

extern "C" void kernel_launch(void* const* d_in, const int* in_sizes, int n_in,
                              void* d_out, int out_size, void* d_ws, size_t ws_size,
                              hipStream_t stream) {
    const float* x  = (const float*)d_in[0];
    const float* y  = (const float*)d_in[1];
    const int*   ei = (const int*)d_in[2];
    const float* w1 = (const float*)d_in[3];
    const float* b1 = (const float*)d_in[4];
    const float* w2 = (const float*)d_in[5];
    const float* b2 = (const float*)d_in[6];

    const int N = in_sizes[1];
    const int E = in_sizes[2] / 2;

    float* out   = (float*)d_out;
    float* yhat  = out;          // [N]
    float* alpha = out + N;      // [E]

    char* ws = (char*)d_ws;
    unsigned long long* bar = (unsigned long long*)ws;                   // 1 u64 (padded 256B)
    unsigned char* P = (unsigned char*)(ws + 256);                       // N*256 int8
    const size_t Pbytes = (size_t)N * 256;
    unsigned long long* agg = (unsigned long long*)(ws + 256 + Pbytes);  // N u64
    unsigned short* evh = (unsigned short*)(ws + 256 + Pbytes + (size_t)N * 8);  // E bf16

    proj_kernel<<<(N + 63) / 64, 256, 0, stream>>>(x, w1, b1, P, agg, N);

    // runtime-validated co-residency for the fused path
    static int maxBlkPerCU = -1;
    if (maxBlkPerCU < 0) {
        hipError_t oe = hipOccupancyMaxActiveBlocksPerMultiprocessor(
            &maxBlkPerCU, edge_decode_coop_kernel, 256, 0);
        if (oe != hipSuccess || maxBlkPerCU < 1) maxBlkPerCU = 0;
    }

    if (maxBlkPerCU >= 8) {
        int nblk = 2048;   // 8 blk/CU x 256 CU — full R2-proven edge concurrency
        hipMemsetAsync(bar, 0, 8, stream);
        void* args[] = {(void*)&P, (void*)&ei, (void*)&y, (void*)&w2, (void*)&b2,
                        (void*)&evh, (void*)&agg, (void*)&bar, (void*)&alpha,
                        (void*)&yhat, (void*)&N, (void*)&E, (void*)&nblk};
        hipLaunchCooperativeKernel((void*)edge_decode_coop_kernel,
                                   dim3(nblk), dim3(256), args, 0, stream);
    } else {
        // proven 3-kernel path (R10/R12: ~197 us)
        edge_logit_kernel<<<2048, 256, 0, stream>>>(P, ei, y, w2, b2, evh, agg, E);
        decode_alpha_kernel<<<1600, 256, 0, stream>>>(ei, agg, evh, alpha, yhat, N, E);
    }
}

// Round 15
// 196.439 us; speedup vs baseline: 1.0096x; 1.0096x over previous
//
#include <hip/hip_runtime.h>

#define QSCALE 44.0f

// ---------- helpers ----------
__device__ __forceinline__ unsigned short f2bf(float f) {
    unsigned u = __float_as_uint(f);
    unsigned r = (u + 0x7fffu + ((u >> 16) & 1u)) >> 16;   // RNE
    return (unsigned short)r;
}
__device__ __forceinline__ float bfu(unsigned short s) {
    return __uint_as_float(((unsigned)s) << 16);
}

// int8 dot over one dword pair: acc += w[i] * relu(a_i + b_i)
__device__ __forceinline__ float dot4_i8(unsigned ax, unsigned bx, const float* w) {
    float acc = 0.f;
#pragma unroll
    for (int i = 0; i < 4; ++i) {
        int va = (int)(char)(ax >> (8 * i));
        int vb = (int)(char)(bx >> (8 * i));
        acc += w[i] * (float)max(va + vb, 0);
    }
    return acc;
}

// full 16-element lane dot + 8-lane reduce -> full 128-dim logit (pre-bias)
__device__ __forceinline__ float edge_dot(const uint4& a, const uint4& b, const float* w2r) {
    float acc;
    acc  = dot4_i8(a.x, b.x, w2r + 0);
    acc += dot4_i8(a.y, b.y, w2r + 4);
    acc += dot4_i8(a.z, b.z, w2r + 8);
    acc += dot4_i8(a.w, b.w, w2r + 12);
    acc += __shfl_xor(acc, 1);
    acc += __shfl_xor(acc, 2);
    acc += __shfl_xor(acc, 4);
    return acc;
}

// packed fixed-point encode: lo = ev*2^16 (u32), hi = y*ev*2^14 (i32)
__device__ __forceinline__ unsigned long long pack_contrib(float ev, float ys) {
    float flo = fminf(ev * 65536.f, 1.0e9f);
    float fhi = fmaxf(fminf(ys * ev * 16384.f, 1.0e9f), -1.0e9f);
    unsigned int qlo = (unsigned int)__float2int_rn(flo);
    int          qhi = __float2int_rn(fhi);
    return ((unsigned long long)(unsigned int)qhi << 32) | (unsigned long long)qlo;
}

__device__ __forceinline__ int q8(float v) {
    return __float2int_rn(fminf(fmaxf(v * QSCALE, -127.f), 127.f)) & 0xff;
}

// ---------- kernel 1: node projection v3b (R9-proven, 12-ish us) — FROZEN ----------
// Block = 256 threads = 64 nodes x 4 j-groups; j0 wave-uniform via readfirstlane ->
// w1 rides the SGPR operand port (s_load stream, zero VALU cost). f32 weights.
__global__ __launch_bounds__(256) void proj_kernel(
    const float* __restrict__ x, const float* __restrict__ w1, const float* __restrict__ b1,
    unsigned char* __restrict__ P, unsigned long long* __restrict__ agg, int N)
{
    __shared__ float xs[64 * 65];                 // 16.6 KB, stride-65 pad (2-way bank alias = free)
    const int t = threadIdx.x;
    const int nloc = t & 63;
    const int n = blockIdx.x * 64 + nloc;
    const int j0 = __builtin_amdgcn_readfirstlane((t >> 6) * 32);   // wave-uniform -> SGPR

    if (t < 64) {
        int nn = blockIdx.x * 64 + t;
        if (nn < N) agg[nn] = 0ull;
    }

    for (int i4 = t; i4 < 64 * 16; i4 += 256) {
        const int row = i4 >> 4, c4 = (i4 & 15) * 4;
        const int nn = blockIdx.x * 64 + row;
        float4 v = make_float4(0.f, 0.f, 0.f, 0.f);
        if (nn < N) v = *(const float4*)&x[(size_t)nn * 64 + c4];
        float* d = &xs[row * 65 + c4];
        d[0] = v.x; d[1] = v.y; d[2] = v.z; d[3] = v.w;
    }
    __syncthreads();

    float accA[32], accB[32];
#pragma unroll
    for (int c = 0; c < 32; ++c) { accA[c] = b1[j0 + c]; accB[c] = 0.f; }

    const float* __restrict__ xrow = &xs[nloc * 65];
    for (int k = 0; k < 64; ++k) {
        const float xv = xrow[k];
        const float* __restrict__ wa = w1 + k * 128 + j0;          // uniform -> s_load
        const float* __restrict__ wb = w1 + (64 + k) * 128 + j0;   // uniform -> s_load
#pragma unroll
        for (int c = 0; c < 32; ++c) {
            accA[c] = fmaf(xv, wa[c], accA[c]);
            accB[c] = fmaf(xv, wb[c], accB[c]);
        }
    }

    if (n < N) {
        unsigned dwA[8], dwB[8];
#pragma unroll
        for (int d = 0; d < 8; ++d) {
            dwA[d] = (unsigned)q8(accA[d * 4 + 0])
                   | ((unsigned)q8(accA[d * 4 + 1]) << 8)
                   | ((unsigned)q8(accA[d * 4 + 2]) << 16)
                   | ((unsigned)q8(accA[d * 4 + 3]) << 24);
            dwB[d] = (unsigned)q8(accB[d * 4 + 0])
                   | ((unsigned)q8(accB[d * 4 + 1]) << 8)
                   | ((unsigned)q8(accB[d * 4 + 2]) << 16)
                   | ((unsigned)q8(accB[d * 4 + 3]) << 24);
        }
        unsigned char* pA = P + (size_t)n * 256 + j0;
        unsigned char* pB = P + (size_t)n * 256 + 128 + j0;
        *(uint4*)(pA)      = make_uint4(dwA[0], dwA[1], dwA[2], dwA[3]);
        *(uint4*)(pA + 16) = make_uint4(dwA[4], dwA[5], dwA[6], dwA[7]);
        *(uint4*)(pB)      = make_uint4(dwB[0], dwB[1], dwB[2], dwB[3]);
        *(uint4*)(pB + 16) = make_uint4(dwB[4], dwB[5], dwB[6], dwB[7]);
    }
}

// ---------- kernel 2: edge logit — single-edge form (R0-proven) + bf16 ev (R10-proven) ----------
// 2048 blocks x 256 = hardware-max wave count. Pinned at the cross-XCD L2-replication
// wall (P=12.8MB vs 4MB/XCD L2): invariant under occupancy, per-wave MLP depth,
// atomic sharding, and body shape (R0/R1/R2/R5/R12).
__global__ __launch_bounds__(256) void edge_logit_kernel(
    const unsigned char* __restrict__ P, const int* __restrict__ ei,
    const float* __restrict__ y,
    const float* __restrict__ w2, const float* __restrict__ b2,
    unsigned short* __restrict__ evh, unsigned long long* __restrict__ agg, int E)
{
    const int gtid = blockIdx.x * 256 + threadIdx.x;
    const int lane = gtid & 7;
    float w2r[16];
#pragma unroll
    for (int c = 0; c < 16; ++c) w2r[c] = w2[lane * 16 + c] * (1.0f / QSCALE);
    const float b2s = b2[0];

    const int slot = gtid >> 3;
    const int nslots = (gridDim.x * 256) >> 3;
    const int lo16 = lane * 16;

    for (int e = slot; e < E; e += nslots) {
        const int s = ei[e];
        const int d = ei[E + e];
        const uint4 a = *(const uint4*)(P + (size_t)s * 256 + lo16);
        const uint4 b = *(const uint4*)(P + (size_t)d * 256 + 128 + lo16);

        const float acc = edge_dot(a, b, w2r);

        if (lane == 0) {
            const float ev = __expf(acc + b2s);
            evh[e] = f2bf(ev);
            atomicAdd(&agg[d], pack_contrib(ev, y[s]));
        }
    }
}

// ---------- kernel 3: decode (yhat) + alpha normalize — bf16 ev in, f32 alpha out ----------
__global__ __launch_bounds__(256) void decode_alpha_kernel(
    const int* __restrict__ ei, const unsigned long long* __restrict__ agg,
    const unsigned short* __restrict__ evh, float* __restrict__ alpha,
    float* __restrict__ yhat, int N, int E)
{
    const int gtid = blockIdx.x * 256 + threadIdx.x;
    const int ntot = gridDim.x * 256;

    for (int i = gtid; i < N; i += ntot) {
        unsigned long long v = agg[i];
        unsigned int lo = (unsigned int)(v & 0xffffffffull);
        int          hi = (int)(v >> 32);
        yhat[i] = (lo != 0u) ? 4.0f * (float)hi / (float)lo : 0.f;   // (hi/2^14)/(lo/2^16)
    }

    for (int base = gtid * 4; base < E; base += ntot * 4) {
        if (base + 3 < E) {
            const int4 d4 = *(const int4*)&ei[E + base];
            const ushort4 eh = *(const ushort4*)&evh[base];
            const unsigned int l0 = (unsigned int)(agg[d4.x] & 0xffffffffull);
            const unsigned int l1 = (unsigned int)(agg[d4.y] & 0xffffffffull);
            const unsigned int l2 = (unsigned int)(agg[d4.z] & 0xffffffffull);
            const unsigned int l3 = (unsigned int)(agg[d4.w] & 0xffffffffull);
            float4 av;
            av.x = l0 ? bfu(eh.x) * (65536.0f / (float)l0) : 0.f;
            av.y = l1 ? bfu(eh.y) * (65536.0f / (float)l1) : 0.f;
            av.z = l2 ? bfu(eh.z) * (65536.0f / (float)l2) : 0.f;
            av.w = l3 ? bfu(eh.w) * (65536.0f / (float)l3) : 0.f;
            *(float4*)&alpha[base] = av;
        } else {
            for (int e = base; e < E; ++e) {
                const unsigned int lo = (unsigned int)(agg[ei[E + e]] & 0xffffffffull);
                alpha[e] = lo ? bfu(evh[e]) * (65536.0f / (float)lo) : 0.f;
            }
        }
    }
}

extern "C" void kernel_launch(void* const* d_in, const int* in_sizes, int n_in,
                              void* d_out, int out_size, void* d_ws, size_t ws_size,
                              hipStream_t stream) {
    const float* x  = (const float*)d_in[0];
    const float* y  = (const float*)d_in[1];
    const int*   ei = (const int*)d_in[2];
    const float* w1 = (const float*)d_in[3];
    const float* b1 = (const float*)d_in[4];
    const float* w2 = (const float*)d_in[5];
    const float* b2 = (const float*)d_in[6];

    const int N = in_sizes[1];
    const int E = in_sizes[2] / 2;

    float* out   = (float*)d_out;
    float* yhat  = out;          // [N]
    float* alpha = out + N;      // [E]

    char* ws = (char*)d_ws;
    unsigned char* P = (unsigned char*)ws;                         // N*256 int8 = 12.8 MB
    const size_t Pbytes = (size_t)N * 256;
    unsigned long long* agg = (unsigned long long*)(ws + Pbytes);  // N u64
    unsigned short* evh = (unsigned short*)(ws + Pbytes + (size_t)N * 8);  // E bf16 = 3.2 MB

    proj_kernel<<<(N + 63) / 64, 256, 0, stream>>>(x, w1, b1, P, agg, N);
    edge_logit_kernel<<<2048, 256, 0, stream>>>(P, ei, y, w2, b2, evh, agg, E);
    decode_alpha_kernel<<<1600, 256, 0, stream>>>(ei, agg, evh, alpha, yhat, N, E);
}